// Round 12
// baseline (136.564 us; speedup 1.0000x reference)
//
#include <hip/hip_runtime.h>
#include <hip/hip_bf16.h>

#define NROW 8192
#define DDIM 512
#define MARGIN 0.2f

typedef __bf16 bf16x8 __attribute__((ext_vector_type(8)));
typedef float f32x4 __attribute__((ext_vector_type(4)));

__device__ __forceinline__ void gload16(const void* g, void* l) {
    __builtin_amdgcn_global_load_lds(
        (const __attribute__((address_space(1))) void*)g,
        (__attribute__((address_space(3))) void*)l, 16, 0, 0);
}

#define BAR() __builtin_amdgcn_s_barrier()

// ---------------------------------------------------------------------------
// prep: blocks 0..N-1 handle im (convert + idat={||im||^2, MARGIN+||im-s||}),
//       N..2N-1 handle ex (convert + ||ex||^2)
// ---------------------------------------------------------------------------
__global__ __launch_bounds__(256) void prep_kernel(
    const float* __restrict__ im, const float* __restrict__ s,
    const float* __restrict__ ex,
    ushort* __restrict__ Abf, ushort* __restrict__ Bbf,
    float2* __restrict__ idat, float* __restrict__ exsq) {
    int b = blockIdx.x;
    bool isim = b < NROW;
    int row = isim ? b : b - NROW;
    const float* src = isim ? im : ex;
    ushort* dst = isim ? Abf : Bbf;
    int tid = threadIdx.x;

    float2 v = ((const float2*)(src + (size_t)row * DDIM))[tid];
    __hip_bfloat16 hx = __float2bfloat16(v.x);
    __hip_bfloat16 hy = __float2bfloat16(v.y);
    unsigned packed = (unsigned)*(const ushort*)&hx | ((unsigned)*(const ushort*)&hy << 16);
    ((unsigned*)(dst + (size_t)row * DDIM))[tid] = packed;

    float ssq = v.x * v.x + v.y * v.y;
    float dsq = 0.f;
    if (isim) {
        float2 sv = ((const float2*)(s + (size_t)row * DDIM))[tid];
        float dx = v.x - sv.x, dy = v.y - sv.y;
        dsq = dx * dx + dy * dy;
    }
    #pragma unroll
    for (int off = 32; off > 0; off >>= 1) {
        ssq += __shfl_down(ssq, off);
        dsq += __shfl_down(dsq, off);
    }
    __shared__ float sred[8];
    int lane = tid & 63, w = tid >> 6;
    if (lane == 0) { sred[w] = ssq; sred[4 + w] = dsq; }
    __syncthreads();
    if (tid == 0) {
        float S = sred[0] + sred[1] + sred[2] + sred[3];
        float Dd = sred[4] + sred[5] + sred[6] + sred[7];
        if (isim) idat[row] = make_float2(S, MARGIN + sqrtf(Dd));
        else      exsq[row] = S;
    }
}

// ---------------------------------------------------------------------------
// 256x256 GEMM + fused epilogue (round-10 structure, UNCHANGED) plus a
// DIAGNOSTIC TAIL: 8 pseudo-K-tiles of the identical MFMA-cluster/barrier
// skeleton with ZERO memory traffic, accumulating exact-0 (za=0) into acc.
// Purpose: rounds 2/8/9/10 (four different schedules) all pin at 20-22%
// MfmaUtil; dur delta of this tail vs round-10 measures the pure
// MFMA+barrier skeleton cost at 8 waves/CU, splitting
// {MFMA-issue/dep-bound} from {memory/overlap-bound}.
// ---------------------------------------------------------------------------
__global__ __launch_bounds__(512) void gemm_cost_kernel(
    const ushort* __restrict__ Abf, const ushort* __restrict__ Bbf,
    const float2* __restrict__ idat, const float* __restrict__ exsq,
    float* __restrict__ partials) {
    __shared__ __align__(16) ushort sA[2][16384];  // 64 KB
    __shared__ __align__(16) ushort sB[2][16384];  // 64 KB
    __shared__ float redbuf[8];

    // XCD-aware square-window mapping (bijective over 32x32 tiles)
    int bid0 = blockIdx.x;
    int c = bid0 & 7;            // assumed XCD id
    int sq = bid0 >> 3;          // 0..127 sequence within XCD
    int bi = c * 4 + (sq & 3);
    int bj = (sq >> 5) * 8 + ((sq >> 2) & 7);
    int bid = bi * 32 + bj;      // for partials indexing (bijective)
    int ibase = bi * 256, jbase = bj * 256;
    int tid = threadIdx.x, lane = tid & 63, w = tid >> 6;
    int wr = w >> 2, wc = w & 3;

    // staging per-thread constants
    int r = tid >> 3;            // 0..63 (second load: r+64)
    int pc = tid & 7;            // physical 16B chunk in row
    int lc = pc ^ (r & 7);       // logical chunk (source pre-swizzle)
    const ushort* aG = Abf + (size_t)(ibase + r) * DDIM + lc * 8;
    const ushort* bG = Bbf + (size_t)(jbase + r) * DDIM + lc * 8;
    ushort* aL = &sA[0][0] + r * 64 + pc * 8;
    ushort* bL = &sB[0][0] + r * 64 + pc * 8;

    auto STAGE = [&](int h) {
        if (h >= 32) return;
        int kt = h >> 2, q = h & 3;
        if (q < 2) {
            const ushort* g = aG + q * (128 * DDIM) + kt * 64;
            ushort* l = aL + (kt & 1) * 16384 + q * 8192;
            gload16(g, l);
            gload16(g + 64 * DDIM, l + 4096);
        } else {
            int qq = q - 2;
            const ushort* g = bG + qq * (128 * DDIM) + kt * 64;
            ushort* l = bL + (kt & 1) * 16384 + qq * 8192;
            gload16(g, l);
            gload16(g + 64 * DDIM, l + 4096);
        }
    };

    // ds_read per-thread constants (read-side swizzle: chunk ^= row&7 = lane&7)
    int l15 = lane & 15;
    int pc0 = (((lane >> 4) ^ (lane & 7)) * 8);  // ushort offset, ks=0
    int pc1 = pc0 ^ 32;                          // ks=1 (^4 chunks)
    int aoff = (wr * 128 + l15) * 64;
    int boff = (wc * 64 + l15) * 64;

    f32x4 acc[8][4] = {};

    // prologue: tiles 0 and 1 fully staged (16 loads); vmcnt(8) seals tile 0
    STAGE(0); STAGE(1); STAGE(2); STAGE(3);
    STAGE(4); STAGE(5); STAGE(6); STAGE(7);
    asm volatile("s_waitcnt vmcnt(8)" ::: "memory");
    BAR();

    #pragma unroll
    for (int t = 0; t < 8; ++t) {
        const ushort* pA = &sA[t & 1][0];
        const ushort* pB = &sB[t & 1][0];
        bf16x8 a[8][2], b0[2][2], b1[2][2];

        #pragma unroll
        for (int m = 0; m < 8; ++m) {
            a[m][0] = *(const bf16x8*)(pA + aoff + m * 1024 + pc0);
            a[m][1] = *(const bf16x8*)(pA + aoff + m * 1024 + pc1);
        }
        #pragma unroll
        for (int n = 0; n < 2; ++n) {
            b0[n][0] = *(const bf16x8*)(pB + boff + n * 1024 + pc0);
            b0[n][1] = *(const bf16x8*)(pB + boff + n * 1024 + pc1);
        }
        __builtin_amdgcn_s_setprio(1);
        #pragma unroll
        for (int m = 0; m < 8; ++m)
            #pragma unroll
            for (int n = 0; n < 2; ++n) {
                acc[m][n] = __builtin_amdgcn_mfma_f32_16x16x32_bf16(a[m][0], b0[n][0], acc[m][n], 0, 0, 0);
                acc[m][n] = __builtin_amdgcn_mfma_f32_16x16x32_bf16(a[m][1], b0[n][1], acc[m][n], 0, 0, 0);
            }
        __builtin_amdgcn_s_setprio(0);
        #pragma unroll
        for (int n = 0; n < 2; ++n) {
            b1[n][0] = *(const bf16x8*)(pB + boff + (n + 2) * 1024 + pc0);
            b1[n][1] = *(const bf16x8*)(pB + boff + (n + 2) * 1024 + pc1);
        }
        __builtin_amdgcn_s_setprio(1);
        #pragma unroll
        for (int m = 0; m < 8; ++m)
            #pragma unroll
            for (int n = 0; n < 2; ++n) {
                acc[m][n + 2] = __builtin_amdgcn_mfma_f32_16x16x32_bf16(a[m][0], b1[n][0], acc[m][n + 2], 0, 0, 0);
                acc[m][n + 2] = __builtin_amdgcn_mfma_f32_16x16x32_bf16(a[m][1], b1[n][1], acc[m][n + 2], 0, 0, 0);
            }
        __builtin_amdgcn_s_setprio(0);

        BAR();
        STAGE(4 * (t + 2) + 0); STAGE(4 * (t + 2) + 1);
        STAGE(4 * (t + 2) + 2); STAGE(4 * (t + 2) + 3);
        if (t < 6)       asm volatile("s_waitcnt vmcnt(8)" ::: "memory");
        else if (t == 6) asm volatile("s_waitcnt vmcnt(0)" ::: "memory");
        BAR();
    }

    // ---- DIAGNOSTIC TAIL: MFMA-only skeleton, exact-zero contribution ----
    // za = 0 -> acc[m][n] += 0*0 = unchanged (MFMA intrinsic is opaque to the
    // compiler, epilogue reads acc -> not DCE'd). Same cluster sizes, setprio,
    // barrier and (trivially-satisfied) vmcnt pattern as the real loop, but
    // no ds_read / no staging. Dur delta vs round 10 = skeleton cost.
    {
        bf16x8 za = {};
        #pragma unroll
        for (int t = 0; t < 8; ++t) {
            __builtin_amdgcn_s_setprio(1);
            #pragma unroll
            for (int m = 0; m < 8; ++m)
                #pragma unroll
                for (int n = 0; n < 2; ++n) {
                    acc[m][n] = __builtin_amdgcn_mfma_f32_16x16x32_bf16(za, za, acc[m][n], 0, 0, 0);
                    acc[m][n] = __builtin_amdgcn_mfma_f32_16x16x32_bf16(za, za, acc[m][n], 0, 0, 0);
                }
            __builtin_amdgcn_s_setprio(0);
            __builtin_amdgcn_s_setprio(1);
            #pragma unroll
            for (int m = 0; m < 8; ++m)
                #pragma unroll
                for (int n = 0; n < 2; ++n) {
                    acc[m][n + 2] = __builtin_amdgcn_mfma_f32_16x16x32_bf16(za, za, acc[m][n + 2], 0, 0, 0);
                    acc[m][n + 2] = __builtin_amdgcn_mfma_f32_16x16x32_bf16(za, za, acc[m][n + 2], 0, 0, 0);
                }
            __builtin_amdgcn_s_setprio(0);
            BAR();
            asm volatile("s_waitcnt vmcnt(8)" ::: "memory");
            BAR();
        }
    }

    // epilogue: cost = max(idat.y - sqrt(max(idat.x + exsq[j] - 2*dot, 0)), 0)
    // C/D layout: col = lane&15, row = (lane>>4)*4 + reg
    float jt[4];
    #pragma unroll
    for (int n = 0; n < 4; ++n) jt[n] = exsq[jbase + wc * 64 + n * 16 + l15];
    int r0 = (lane >> 4) * 4;
    float lsum = 0.f;
    #pragma unroll
    for (int m = 0; m < 8; ++m) {
        #pragma unroll
        for (int rg = 0; rg < 4; ++rg) {
            int i = ibase + wr * 128 + m * 16 + r0 + rg;
            float2 id = idat[i];
            #pragma unroll
            for (int n = 0; n < 4; ++n) {
                float d2 = fmaxf(id.x + jt[n] - 2.0f * acc[m][n][rg], 0.0f);
                lsum += fmaxf(id.y - sqrtf(d2), 0.0f);
            }
        }
    }
    #pragma unroll
    for (int off = 32; off > 0; off >>= 1) lsum += __shfl_down(lsum, off);
    if (lane == 0) redbuf[w] = lsum;
    __syncthreads();
    if (tid == 0) {
        float tot = 0.f;
        #pragma unroll
        for (int q = 0; q < 8; ++q) tot += redbuf[q];
        partials[bid] = tot;
    }
}

// ---------------------------------------------------------------------------
// deterministic final reduce: 1024 partials -> mean
// ---------------------------------------------------------------------------
__global__ __launch_bounds__(256) void finalize_kernel(
    const float* __restrict__ partials, float* __restrict__ out) {
    float acc = 0.f;
    for (int t = threadIdx.x; t < 1024; t += 256) acc += partials[t];
    #pragma unroll
    for (int off = 32; off > 0; off >>= 1) acc += __shfl_down(acc, off);
    __shared__ float sred[4];
    int lane = threadIdx.x & 63, w = threadIdx.x >> 6;
    if (lane == 0) sred[w] = acc;
    __syncthreads();
    if (threadIdx.x == 0) {
        float total = sred[0] + sred[1] + sred[2] + sred[3];
        out[0] = total * (1.0f / (8192.0f * 8192.0f));  // exact pow2 scale
    }
}

extern "C" void kernel_launch(void* const* d_in, const int* in_sizes, int n_in,
                              void* d_out, int out_size, void* d_ws, size_t ws_size,
                              hipStream_t stream) {
    const float* im = (const float*)d_in[0];
    const float* s  = (const float*)d_in[1];
    const float* ex = (const float*)d_in[2];

    // workspace layout (~16.2 MB)
    char* ws = (char*)d_ws;
    ushort* Abf   = (ushort*)(ws);                       // 8 MB
    ushort* Bbf   = (ushort*)(ws + 8388608);             // 8 MB
    float2* idat  = (float2*)(ws + 16777216);            // 64 KB
    float*  exsq  = (float*)(ws + 16842752);             // 32 KB
    float*  parts = (float*)(ws + 16875520);             // 4 KB

    prep_kernel<<<2 * NROW, 256, 0, stream>>>(im, s, ex, Abf, Bbf, idat, exsq);
    gemm_cost_kernel<<<(NROW / 256) * (NROW / 256), 512, 0, stream>>>(Abf, Bbf, idat, exsq, parts);
    finalize_kernel<<<1, 256, 0, stream>>>(parts, (float*)d_out);
}

// Round 14
// 111.432 us; speedup vs baseline: 1.2255x; 1.2255x over previous
//
#include <hip/hip_runtime.h>
#include <hip/hip_bf16.h>

#define NROW 8192
#define DDIM 512
#define MARGIN 0.2f

typedef __bf16 bf16x8 __attribute__((ext_vector_type(8)));
typedef float f32x4 __attribute__((ext_vector_type(4)));

__device__ __forceinline__ void gload16(const void* g, void* l) {
    __builtin_amdgcn_global_load_lds(
        (const __attribute__((address_space(1))) void*)g,
        (__attribute__((address_space(3))) void*)l, 16, 0, 0);
}

#define BAR() __builtin_amdgcn_s_barrier()

// ---------------------------------------------------------------------------
// prep: blocks 0..N-1 handle im (convert + idat={||im||^2, MARGIN+||im-s||}),
//       N..2N-1 handle ex (convert + ||ex||^2)
// ---------------------------------------------------------------------------
__global__ __launch_bounds__(256) void prep_kernel(
    const float* __restrict__ im, const float* __restrict__ s,
    const float* __restrict__ ex,
    ushort* __restrict__ Abf, ushort* __restrict__ Bbf,
    float2* __restrict__ idat, float* __restrict__ exsq) {
    int b = blockIdx.x;
    bool isim = b < NROW;
    int row = isim ? b : b - NROW;
    const float* src = isim ? im : ex;
    ushort* dst = isim ? Abf : Bbf;
    int tid = threadIdx.x;

    float2 v = ((const float2*)(src + (size_t)row * DDIM))[tid];
    __hip_bfloat16 hx = __float2bfloat16(v.x);
    __hip_bfloat16 hy = __float2bfloat16(v.y);
    unsigned packed = (unsigned)*(const ushort*)&hx | ((unsigned)*(const ushort*)&hy << 16);
    ((unsigned*)(dst + (size_t)row * DDIM))[tid] = packed;

    float ssq = v.x * v.x + v.y * v.y;
    float dsq = 0.f;
    if (isim) {
        float2 sv = ((const float2*)(s + (size_t)row * DDIM))[tid];
        float dx = v.x - sv.x, dy = v.y - sv.y;
        dsq = dx * dx + dy * dy;
    }
    #pragma unroll
    for (int off = 32; off > 0; off >>= 1) {
        ssq += __shfl_down(ssq, off);
        dsq += __shfl_down(dsq, off);
    }
    __shared__ float sred[8];
    int lane = tid & 63, w = tid >> 6;
    if (lane == 0) { sred[w] = ssq; sred[4 + w] = dsq; }
    __syncthreads();
    if (tid == 0) {
        float S = sred[0] + sred[1] + sred[2] + sred[3];
        float Dd = sred[4] + sred[5] + sred[6] + sred[7];
        if (isim) idat[row] = make_float2(S, MARGIN + sqrtf(Dd));
        else      exsq[row] = S;
    }
}

// ---------------------------------------------------------------------------
// 128x128 GEMM + fused epilogue. 4 waves (2x2), BK=64, dbuf LDS = 64 KB ->
// TWO blocks co-resident per CU with INDEPENDENT barrier groups.
// Round-12 diagnostic proved the MFMA+barrier skeleton runs at ~100% MFMA
// rate; the 94us loop = 27.5us MFMA + ~31us LDS wall + ~35us serialization
// (symmetric barrier-locked waves: LDS phase and MFMA phase never overlap).
// Two async blocks per CU de-phase -> one block's MFMA overlaps the other's
// LDS reads (m114 mechanism). Each SIMD hosts 1 wave from each block.
// LDS rows 128B, chunk16 XOR swizzle: phys = logical ^ (row&7) (both sides).
// Half-tiles (8KB): h = 4*kt + q, q: 0=A rows0-63, 1=A 64-127, 2=B 0-63,
// 3=B 64-127. Prologue stages tiles 0,1 (16 loads), vmcnt(8) seals tile 0.
// Iter t: reads+MFMA tile t, BAR, STAGE tile t+2 (8 loads), vmcnt(8) seals
// t+1 (vmcnt(0) at t==6), BAR. Same validated ledger as round 10.
// XCD map: XCD c owns bi in [8c, 8c+8) -> A panel 1MB L2-resident; B
// streamed in 8x8 windows (1MB A + 1MB B co-resident < 4MB L2).
// ---------------------------------------------------------------------------
__global__ __launch_bounds__(256, 2) void gemm_cost_kernel(
    const ushort* __restrict__ Abf, const ushort* __restrict__ Bbf,
    const float2* __restrict__ idat, const float* __restrict__ exsq,
    float* __restrict__ partials) {
    __shared__ __align__(16) ushort sA[2][8192];  // 32 KB
    __shared__ __align__(16) ushort sB[2][8192];  // 32 KB
    __shared__ float redbuf[4];

    // XCD-aware window mapping (bijective over 64x64 tiles)
    int bid0 = blockIdx.x;
    int c = bid0 & 7;            // assumed XCD id
    int sq = bid0 >> 3;          // 0..511 within XCD
    int win = sq >> 6;           // 0..7  bj window
    int pos = sq & 63;           // 0..63 within 8x8 window
    int bi = c * 8 + (pos & 7);
    int bj = win * 8 + (pos >> 3);
    int bid = bi * 64 + bj;      // bijective, for partials
    int ibase = bi * 128, jbase = bj * 128;
    int tid = threadIdx.x, lane = tid & 63, w = tid >> 6;
    int wr = w >> 1, wc = w & 1;

    // staging per-thread constants: chunk ct = tid (rows 0-31) / +256 (32-63)
    int r = tid >> 3;            // 0..31
    int pc = tid & 7;            // physical 16B chunk in row
    int lc = pc ^ (r & 7);       // logical chunk (source pre-swizzle; row+32 same mod 8)
    const ushort* aG = Abf + (size_t)(ibase + r) * DDIM + lc * 8;
    const ushort* bG = Bbf + (size_t)(jbase + r) * DDIM + lc * 8;
    ushort* aL = &sA[0][0] + r * 64 + pc * 8;
    ushort* bL = &sB[0][0] + r * 64 + pc * 8;

    auto STAGE = [&](int h) {
        if (h >= 32) return;
        int kt = h >> 2, q = h & 3;
        if (q < 2) {
            const ushort* g = aG + q * (64 * DDIM) + kt * 64;
            ushort* l = aL + (kt & 1) * 8192 + q * 4096;
            gload16(g, l);
            gload16(g + 32 * DDIM, l + 2048);
        } else {
            int qq = q - 2;
            const ushort* g = bG + qq * (64 * DDIM) + kt * 64;
            ushort* l = bL + (kt & 1) * 8192 + qq * 4096;
            gload16(g, l);
            gload16(g + 32 * DDIM, l + 2048);
        }
    };

    // ds_read per-thread constants (read-side swizzle: chunk ^= row&7 = lane&7)
    int l15 = lane & 15;
    int pc0 = (((lane >> 4) ^ (lane & 7)) * 8);  // ushort offset, ks=0
    int pc1 = pc0 ^ 32;                          // ks=1 (^4 chunks)
    int aoff = (wr * 64 + l15) * 64;
    int boff = (wc * 64 + l15) * 64;

    f32x4 acc[4][4] = {};

    // prologue: tiles 0 and 1 fully staged (16 loads); vmcnt(8) seals tile 0
    STAGE(0); STAGE(1); STAGE(2); STAGE(3);
    STAGE(4); STAGE(5); STAGE(6); STAGE(7);
    asm volatile("s_waitcnt vmcnt(8)" ::: "memory");
    BAR();

    #pragma unroll
    for (int t = 0; t < 8; ++t) {
        const ushort* pA = &sA[t & 1][0];
        const ushort* pB = &sB[t & 1][0];
        bf16x8 a[4][2], b[4][2];

        #pragma unroll
        for (int m = 0; m < 4; ++m) {
            a[m][0] = *(const bf16x8*)(pA + aoff + m * 1024 + pc0);
            a[m][1] = *(const bf16x8*)(pA + aoff + m * 1024 + pc1);
        }
        #pragma unroll
        for (int n = 0; n < 4; ++n) {
            b[n][0] = *(const bf16x8*)(pB + boff + n * 1024 + pc0);
            b[n][1] = *(const bf16x8*)(pB + boff + n * 1024 + pc1);
        }
        __builtin_amdgcn_s_setprio(1);
        #pragma unroll
        for (int m = 0; m < 4; ++m)
            #pragma unroll
            for (int n = 0; n < 4; ++n) {
                acc[m][n] = __builtin_amdgcn_mfma_f32_16x16x32_bf16(a[m][0], b[n][0], acc[m][n], 0, 0, 0);
                acc[m][n] = __builtin_amdgcn_mfma_f32_16x16x32_bf16(a[m][1], b[n][1], acc[m][n], 0, 0, 0);
            }
        __builtin_amdgcn_s_setprio(0);

        // reads all landed (consumed by lgkm-waited MFMAs); BAR -> block-wide
        BAR();
        STAGE(4 * (t + 2) + 0); STAGE(4 * (t + 2) + 1);
        STAGE(4 * (t + 2) + 2); STAGE(4 * (t + 2) + 3);
        if (t < 6)       asm volatile("s_waitcnt vmcnt(8)" ::: "memory");
        else if (t == 6) asm volatile("s_waitcnt vmcnt(0)" ::: "memory");
        BAR();   // block-wide seal of tile t+1 (vmcnt is per-wave)
    }

    // epilogue: cost = max(idat.y - sqrt(max(idat.x + exsq[j] - 2*dot, 0)), 0)
    // C/D layout: col = lane&15, row = (lane>>4)*4 + reg
    float jt[4];
    #pragma unroll
    for (int n = 0; n < 4; ++n) jt[n] = exsq[jbase + wc * 64 + n * 16 + l15];
    int r0 = (lane >> 4) * 4;
    float lsum = 0.f;
    #pragma unroll
    for (int m = 0; m < 4; ++m) {
        #pragma unroll
        for (int rg = 0; rg < 4; ++rg) {
            int i = ibase + wr * 64 + m * 16 + r0 + rg;
            float2 id = idat[i];
            #pragma unroll
            for (int n = 0; n < 4; ++n) {
                float d2 = fmaxf(id.x + jt[n] - 2.0f * acc[m][n][rg], 0.0f);
                lsum += fmaxf(id.y - sqrtf(d2), 0.0f);
            }
        }
    }
    #pragma unroll
    for (int off = 32; off > 0; off >>= 1) lsum += __shfl_down(lsum, off);
    if (lane == 0) redbuf[w] = lsum;
    __syncthreads();
    if (tid == 0) partials[bid] = redbuf[0] + redbuf[1] + redbuf[2] + redbuf[3];
}

// ---------------------------------------------------------------------------
// deterministic final reduce: 4096 partials -> mean
// ---------------------------------------------------------------------------
__global__ __launch_bounds__(256) void finalize_kernel(
    const float* __restrict__ partials, float* __restrict__ out) {
    float acc = 0.f;
    for (int t = threadIdx.x; t < 4096; t += 256) acc += partials[t];
    #pragma unroll
    for (int off = 32; off > 0; off >>= 1) acc += __shfl_down(acc, off);
    __shared__ float sred[4];
    int lane = threadIdx.x & 63, w = threadIdx.x >> 6;
    if (lane == 0) sred[w] = acc;
    __syncthreads();
    if (threadIdx.x == 0) {
        float total = sred[0] + sred[1] + sred[2] + sred[3];
        out[0] = total * (1.0f / (8192.0f * 8192.0f));  // exact pow2 scale
    }
}

extern "C" void kernel_launch(void* const* d_in, const int* in_sizes, int n_in,
                              void* d_out, int out_size, void* d_ws, size_t ws_size,
                              hipStream_t stream) {
    const float* im = (const float*)d_in[0];
    const float* s  = (const float*)d_in[1];
    const float* ex = (const float*)d_in[2];

    // workspace layout (~16.9 MB)
    char* ws = (char*)d_ws;
    ushort* Abf   = (ushort*)(ws);                       // 8 MB
    ushort* Bbf   = (ushort*)(ws + 8388608);             // 8 MB
    float2* idat  = (float2*)(ws + 16777216);            // 64 KB
    float*  exsq  = (float*)(ws + 16842752);             // 32 KB
    float*  parts = (float*)(ws + 16875520);             // 16 KB

    prep_kernel<<<2 * NROW, 256, 0, stream>>>(im, s, ex, Abf, Bbf, idat, exsq);
    gemm_cost_kernel<<<(NROW / 128) * (NROW / 128), 256, 0, stream>>>(Abf, Bbf, idat, exsq, parts);
    finalize_kernel<<<1, 256, 0, stream>>>(parts, (float*)d_out);
}